// Round 19
// baseline (1734.495 us; speedup 1.0000x reference)
//
#include <hip/hip_runtime.h>
#include <hip/hip_cooperative_groups.h>

namespace cg = cooperative_groups;

#define DIM 64
#define BIN_SHIFT 8          // 256 nodes per bin
#define BCAP 5120            // staging capacity per bin (entries)

typedef __attribute__((ext_vector_type(8))) _Float16 half8;
typedef __attribute__((ext_vector_type(4))) _Float16 half4;
typedef __attribute__((ext_vector_type(4))) float floatx4;

// ---------------------------------------------------------------------------
// Binning pass A: per-block 512-bin histogram of col>>8 -> blockhist.
// ---------------------------------------------------------------------------
__launch_bounds__(256)
__global__ void hist_kernel(const int* __restrict__ col,
                            int* __restrict__ blockhist, int E) {
    __shared__ int hist[512];
    int tid = threadIdx.x;
    for (int i = tid; i < 512; i += 256) hist[i] = 0;
    __syncthreads();
    int e0 = blockIdx.x * 4096;
    #pragma unroll
    for (int k = 0; k < 16; ++k) {
        int e = e0 + tid + k * 256;
        if (e < E) atomicAdd(&hist[col[e] >> BIN_SHIFT], 1);
    }
    __syncthreads();
    for (int i = tid; i < 512; i += 256)
        blockhist[(size_t)blockIdx.x * 512 + i] = hist[i];
}

// ---------------------------------------------------------------------------
// Binning pass B: one block per bin; exclusive scan of blockhist over the
// edge-blocks -> per-(block,bin) base offsets; bin totals -> bin_cursor.
// ---------------------------------------------------------------------------
__global__ void scan_hist_kernel(const int* __restrict__ blockhist,
                                 int* __restrict__ offs_g,
                                 int* __restrict__ bin_cursor, int nb) {
    __shared__ int s[256];
    int bin = blockIdx.x, t = threadIdx.x;
    int h0 = (2 * t < nb)     ? blockhist[(size_t)(2 * t) * 512 + bin]     : 0;
    int h1 = (2 * t + 1 < nb) ? blockhist[(size_t)(2 * t + 1) * 512 + bin] : 0;
    int ps = h0 + h1;
    s[t] = ps;
    __syncthreads();
    for (int d = 1; d < 256; d <<= 1) {
        int v = (t >= d) ? s[t - d] : 0;
        __syncthreads();
        s[t] += v;
        __syncthreads();
    }
    int ex = s[t] - ps;
    if (2 * t < nb)     offs_g[(size_t)(2 * t) * 512 + bin] = ex;
    if (2 * t + 1 < nb) offs_g[(size_t)(2 * t + 1) * 512 + bin] = ex + h0;
    if (t == 255) bin_cursor[bin] = s[255];
}

// ---------------------------------------------------------------------------
// Binning pass C: in-block counting sort by bin in LDS; deterministic bases
// from offs_g (no global atomics). Staging entries packed to 4B:
// (row<<8)|(col&255).
// ---------------------------------------------------------------------------
__launch_bounds__(256)
__global__ void scatter_edges_kernel(const int* __restrict__ row,
                                     const int* __restrict__ col,
                                     const int* __restrict__ offs_g,
                                     int* __restrict__ staging, int E) {
    __shared__ int hist[512];
    __shared__ int offs[512];
    __shared__ int base[512];
    __shared__ int s[256];
    __shared__ int2 buf[4096];
    int tid = threadIdx.x;
    for (int i = tid; i < 512; i += 256) hist[i] = 0;
    __syncthreads();
    int e0 = blockIdx.x * 4096;
    int c[16], r[16];
    #pragma unroll
    for (int k = 0; k < 16; ++k) {
        int e = e0 + tid + k * 256;
        c[k] = (e < E) ? col[e] : -1;
        r[k] = (e < E) ? row[e] : 0;
        if (c[k] >= 0) atomicAdd(&hist[c[k] >> BIN_SHIFT], 1);
    }
    __syncthreads();
    int h0 = hist[2 * tid], h1 = hist[2 * tid + 1];
    int ps = h0 + h1;
    s[tid] = ps;
    __syncthreads();
    for (int d = 1; d < 256; d <<= 1) {
        int v = (tid >= d) ? s[tid - d] : 0;
        __syncthreads();
        s[tid] += v;
        __syncthreads();
    }
    int ex = s[tid] - ps;
    offs[2 * tid] = ex;
    offs[2 * tid + 1] = ex + h0;
    __syncthreads();
    for (int i = tid; i < 512; i += 256) {
        base[i] = offs_g[(size_t)blockIdx.x * 512 + i];
        hist[i] = 0;
    }
    __syncthreads();
    #pragma unroll
    for (int k = 0; k < 16; ++k) {
        if (c[k] >= 0) {
            int b = c[k] >> BIN_SHIFT;
            int pos = offs[b] + atomicAdd(&hist[b], 1);
            buf[pos] = make_int2(r[k], c[k]);
        }
    }
    __syncthreads();
    int count = (e0 + 4096 <= E) ? 4096 : (E > e0 ? E - e0 : 0);
    for (int i = tid; i < count; i += 256) {
        int2 rc = buf[i];
        int b = rc.y >> BIN_SHIFT;
        staging[(size_t)b * BCAP + base[b] + (i - offs[b])] =
            (rc.x << 8) | (rc.y & 255);
    }
}

// ---------------------------------------------------------------------------
// Per-bin degree count + dinv/rdinv + padded chunk sum bs[b].
// ---------------------------------------------------------------------------
__launch_bounds__(256)
__global__ void count_deg_bins_kernel(const int* __restrict__ staging,
                                      const int* __restrict__ bin_cursor,
                                      int* __restrict__ deg,
                                      float* __restrict__ dinv,
                                      float* __restrict__ rdinv,
                                      int* __restrict__ bs, int N) {
    __shared__ int hist[256];
    __shared__ int red[256];
    int b = blockIdx.x;
    int tid = threadIdx.x;
    hist[tid] = 0;
    __syncthreads();
    int cnt = bin_cursor[b];
    for (int i = tid; i < cnt; i += 256)
        atomicAdd(&hist[staging[(size_t)b * BCAP + i] & 255], 1);
    __syncthreads();
    int n = (b << BIN_SHIFT) + tid;
    int pdeg = 0;
    if (n < N) {
        int dg = hist[tid];
        deg[n] = dg;
        float d = (float)dg + 1.0f;
        dinv[n] = rsqrtf(d);
        rdinv[n] = sqrtf(d);
        pdeg = (dg + 1 + 3) & ~3;
    }
    red[tid] = pdeg;
    __syncthreads();
    for (int d = 128; d > 0; d >>= 1) {
        if (tid < d) red[tid] += red[tid + d];
        __syncthreads();
    }
    if (tid == 0) bs[b] = red[0];
}

__global__ void scan_block_sums_kernel(int* __restrict__ bs, int nb) {
    __shared__ int s[1024];
    int t = threadIdx.x;
    s[t] = (t < nb) ? bs[t] : 0;
    __syncthreads();
    for (int d = 1; d < 1024; d <<= 1) {
        int v = (t >= d) ? s[t - d] : 0;
        __syncthreads();
        s[t] += v;
        __syncthreads();
    }
    if (t < nb) bs[t] = (t == 0) ? 0 : s[t - 1];
}

__global__ void scan_chunks_kernel(const int* __restrict__ deg,
                                   const int* __restrict__ bs,
                                   int* __restrict__ ptr, int N) {
    __shared__ int s[256];
    int b = blockIdx.x, t = threadIdx.x;
    int i = b * 256 + t;
    int v = (i < N) ? ((deg[i] + 1 + 3) & ~3) : 0;
    s[t] = v;
    __syncthreads();
    for (int d = 1; d < 256; d <<= 1) {
        int u = (t >= d) ? s[t - d] : 0;
        __syncthreads();
        s[t] += u;
        __syncthreads();
    }
    if (i < N) {
        int p = bs[b] + s[t] - v;
        ptr[i] = p;
        if (i == N - 1) ptr[N] = p + v;
    }
}

// ---------------------------------------------------------------------------
// CSC fill from bins: one block per bin; LDS cursors. Self-edge, in-edges
// (row = packed>>8), dummy-N padding to x4; 64-int tail pad in last block.
// ---------------------------------------------------------------------------
__launch_bounds__(256)
__global__ void fill_bins_kernel(const int* __restrict__ staging,
                                 const int* __restrict__ bin_cursor,
                                 const int* __restrict__ ptr,
                                 int* __restrict__ srcs, int N, int dummy) {
    __shared__ int cur[256];
    int b = blockIdx.x;
    int tid = threadIdx.x;
    int n = (b << BIN_SHIFT) + tid;
    if (n < N) {
        int p = ptr[n];
        srcs[p] = n;           // self-edge
        cur[tid] = p + 1;
    } else cur[tid] = 0;
    if (b == gridDim.x - 1 && tid < 64)
        srcs[ptr[N] + tid] = dummy;      // tail pad: valid (zero) row ids
    __syncthreads();
    int cnt = bin_cursor[b];
    for (int i = tid; i < cnt; i += 256) {
        int p = staging[(size_t)b * BCAP + i];
        int pos = atomicAdd(&cur[p & 255], 1);
        srcs[pos] = p >> 8;
    }
    __syncthreads();
    if (n < N) {
        int e = cur[tid];            // == ptr[n] + 1 + deg[n]
        int stop = ptr[n + 1];
        for (; e < stop; ++e) srcs[e] = dummy;
    }
}

// ---------------------------------------------------------------------------
// scale_init: v0 (superslab-major fp16 = dinv*x), x16 (row-major fp16), and
// dummy-row zeroing for all 6 superslab buffers (tail threads).
// ---------------------------------------------------------------------------
__global__ void scale_init_slab_kernel(const float* __restrict__ x,
                                       const float* __restrict__ dinv,
                                       _Float16* __restrict__ v0,
                                       _Float16* __restrict__ x16,
                                       _Float16* __restrict__ v1,
                                       _Float16* __restrict__ v3,
                                       _Float16* __restrict__ v7,
                                       _Float16* __restrict__ T1,
                                       _Float16* __restrict__ T2, int N) {
    int t = blockIdx.x * blockDim.x + threadIdx.x;
    if (t < N * 16) {
        int n = t >> 4, d4 = (t & 15) * 4;
        float d = dinv[n];
        float4 a = *(const float4*)(x + (size_t)n * DIM + d4);
        half4 hx;
        hx.x = (_Float16)a.x; hx.y = (_Float16)a.y;
        hx.z = (_Float16)a.z; hx.w = (_Float16)a.w;
        *(half4*)(x16 + (size_t)n * DIM + d4) = hx;
        half4 hv;
        hv.x = (_Float16)(a.x * d); hv.y = (_Float16)(a.y * d);
        hv.z = (_Float16)(a.z * d); hv.w = (_Float16)(a.w * d);
        int S = d4 >> 5, off = d4 & 31;
        *(half4*)(v0 + ((size_t)S * (N + 1) + n) * 32 + off) = hv;
    } else {
        int extra = t - N * 16;      // 96 half4 slots: 6 buffers x 64 halves
        if (extra < 96) {
            _Float16* bufs[6] = {v0, v1, v3, v7, T1, T2};
            int bf = extra >> 4;
            int r = (extra & 15) * 4;
            int S = r >> 5, off = r & 31;
            half4 z = {(_Float16)0.f, (_Float16)0.f,
                       (_Float16)0.f, (_Float16)0.f};
            *(half4*)(bufs[bf] + ((size_t)S * (N + 1) + N) * 32 + off) = z;
        }
    }
}

// ---------------------------------------------------------------------------
// spmv pass body (R13 geometry, measured local optimum): 4 nodes x 4 slots x
// 4 chunks of 16B over 64B rows, straight-line 6-group preload, x4 padding,
// 2-step reduce. XCD-quad pinning: superslab S = (vb&7)>>2 -- preserved
// under grid-stride because gridDim (1536) is a multiple of 8.
// ---------------------------------------------------------------------------
__device__ __forceinline__
void spmv_body(int vb, const int* __restrict__ ptr,
               const int* __restrict__ srcs,
               const float* __restrict__ dinv,
               const _Float16* __restrict__ vin,
               _Float16* __restrict__ vout, int N, int bps, int tid) {
    int S   = (vb & 7) >> 2;
    int blk = ((vb >> 3) << 2) | (vb & 3);
    if (blk >= bps) return;
    const _Float16* vi = vin + (size_t)S * (N + 1) * 32;
    _Float16* vo = vout + (size_t)S * (N + 1) * 32;
    int lane = tid & 63;
    int nq = (lane >> 4) & 3;
    int e  = (lane >> 2) & 3;
    int hc = (lane & 3) << 3;
    int n = blk * 16 + (tid >> 6) * 4 + nq;
    bool valid = n < N;

    int beg = valid ? ptr[n] : 0;
    int end = valid ? ptr[n + 1] : 0;
    float d = valid ? dinv[n] : 0.f;

    int s0 = srcs[beg + e];
    int s1 = srcs[beg + 4 + e];
    int s2 = srcs[beg + 8 + e];
    int s3 = srcs[beg + 12 + e];
    int s4 = srcs[beg + 16 + e];
    int s5 = srcs[beg + 20 + e];

    half8 h0 = *(const half8*)(vi + ((size_t)s0 << 5) + hc);
    half8 h1 = *(const half8*)(vi + ((size_t)s1 << 5) + hc);
    half8 h2 = *(const half8*)(vi + ((size_t)s2 << 5) + hc);
    half8 h3 = *(const half8*)(vi + ((size_t)s3 << 5) + hc);

    half8 z;
    #pragma unroll
    for (int k = 0; k < 8; ++k) z[k] = (_Float16)0.f;

    bool m1 = (beg + 8  <= end);
    bool m2 = (beg + 12 <= end);
    bool m3 = (beg + 16 <= end);
    half8 t01 = h0 + (m1 ? h1 : z);
    half8 t23 = (m2 ? h2 : z) + (m3 ? h3 : z);
    half8 g = t01 + t23;

    float a[8];
    #pragma unroll
    for (int k = 0; k < 8; ++k) a[k] = (float)g[k];

    if (beg + 20 <= end) {
        half8 h4 = *(const half8*)(vi + ((size_t)s4 << 5) + hc);
        #pragma unroll
        for (int k = 0; k < 8; ++k) a[k] += (float)h4[k];
        if (beg + 24 <= end) {
            half8 h5 = *(const half8*)(vi + ((size_t)s5 << 5) + hc);
            #pragma unroll
            for (int k = 0; k < 8; ++k) a[k] += (float)h5[k];
            for (int j = beg + 24; j + 4 <= end; j += 4) {
                int s = srcs[j + e];
                half8 hx = *(const half8*)(vi + ((size_t)s << 5) + hc);
                #pragma unroll
                for (int k = 0; k < 8; ++k) a[k] += (float)hx[k];
            }
        }
    }

    #pragma unroll
    for (int k = 0; k < 8; ++k) {
        a[k] += __shfl_xor(a[k], 4);
        a[k] += __shfl_xor(a[k], 8);
    }
    if (e == 0 && valid) {
        float dd = d * d;
        half8 r;
        #pragma unroll
        for (int k = 0; k < 8; ++k)
            r[k] = (_Float16)(dd * a[k]);
        *(half8*)(vo + ((size_t)n << 5) + hc) = r;
    }
}

// ---------------------------------------------------------------------------
// Persistent cooperative spmv chain: all 7 passes in ONE dispatch with
// grid.sync() between them (replaces 6 launch round-trips + per-pass
// dispatch ramp/drain). Pass sequence: v0->v1->T1->v3->T1->T2->T1->v7.
// ---------------------------------------------------------------------------
__launch_bounds__(256)
__global__ void spmv_chain_kernel(const int* __restrict__ ptr,
                                  const int* __restrict__ srcs,
                                  const float* __restrict__ dinv,
                                  _Float16* __restrict__ v0,
                                  _Float16* __restrict__ v1,
                                  _Float16* __restrict__ v3,
                                  _Float16* __restrict__ v7,
                                  _Float16* __restrict__ T1,
                                  _Float16* __restrict__ T2,
                                  int N, int bps, int nvb) {
    cg::grid_group grid = cg::this_grid();
    int tid = threadIdx.x;
    _Float16* seq[8] = {v0, v1, T1, v3, T1, T2, T1, v7};
    #pragma unroll 1
    for (int pass = 0; pass < 7; ++pass) {
        const _Float16* vin = seq[pass];
        _Float16* vout = seq[pass + 1];
        for (int vb = blockIdx.x; vb < nvb; vb += gridDim.x)
            spmv_body(vb, ptr, srcs, dinv, vin, vout, N, bps, tid);
        grid.sync();
    }
}

// ---------------------------------------------------------------------------
// make_wfrag: folded effective weights, fp16, MFMA B-fragment order.
// Fold: cat@W = x@W3 + p1@(W0-W3+W4) + p3@(W1-W4+W5) + p7@(W2-W5)
// ---------------------------------------------------------------------------
__global__ void make_wfrag_kernel(const float* __restrict__ W,
                                  _Float16* __restrict__ wf) {
    int idx = blockIdx.x * blockDim.x + threadIdx.x;   // 16384
    if (idx < 16384) {
        int j = idx & 7;
        int lane = (idx >> 3) & 63;
        int t = (idx >> 9) & 7;
        int dt = idx >> 12;
        int col = lane & 15, quad = lane >> 4;
        int d = dt * 16 + col;
        int kk = t * 32 + quad * 8 + j;
        int src = kk >> 6, k = kk & 63;
        float v;
        if (src == 0)      v = W[(3 * 64 + k) * 64 + d];
        else if (src == 1) v = W[(0 * 64 + k) * 64 + d]
                             - W[(3 * 64 + k) * 64 + d]
                             + W[(4 * 64 + k) * 64 + d];
        else if (src == 2) v = W[(1 * 64 + k) * 64 + d]
                             - W[(4 * 64 + k) * 64 + d]
                             + W[(5 * 64 + k) * 64 + d];
        else               v = W[(2 * 64 + k) * 64 + d]
                             - W[(5 * 64 + k) * 64 + d];
        wf[idx] = (_Float16)v;
    }
}

// ---------------------------------------------------------------------------
// MFMA combine: no LDS, no syncthreads. A-fragments direct from global;
// B-fragments from the 32 KB fragment-ordered wf table. One wave = one
// 16-node group, all 64 output dims (32 mfma).
// ---------------------------------------------------------------------------
__launch_bounds__(256)
__global__ void combine_mfma_kernel(const _Float16* __restrict__ x16,
                                    const _Float16* __restrict__ v1,
                                    const _Float16* __restrict__ v3,
                                    const _Float16* __restrict__ v7,
                                    const float* __restrict__ rdinv,
                                    const _Float16* __restrict__ wf,
                                    const float* __restrict__ bias,
                                    float* __restrict__ out, int N) {
    int tid = threadIdx.x;
    int lane = tid & 63, w = tid >> 6;
    int quad = lane >> 4, col = lane & 15;

    float bv[4];
    #pragma unroll
    for (int dt = 0; dt < 4; ++dt) bv[dt] = bias[dt * 16 + col];

    int bps = (N + 15) / 16;
    size_t N1 = (size_t)N + 1;
    for (int g = blockIdx.x * 4 + w; g < bps; g += gridDim.x * 4) {
        int n0 = g * 16;
        int n = n0 + col;
        int nl = (n < N) ? n : 0;
        _Float16 hrd = (_Float16)rdinv[nl];

        half8 a[8];
        a[0] = *(const half8*)(x16 + (size_t)nl * DIM + quad * 8);
        a[1] = *(const half8*)(x16 + (size_t)nl * DIM + 32 + quad * 8);
        const _Float16* vs[3] = {v1, v3, v7};
        #pragma unroll
        for (int sI = 0; sI < 3; ++sI) {
            #pragma unroll
            for (int hf = 0; hf < 2; ++hf) {
                half8 hv = *(const half8*)(vs[sI] + ((size_t)hf * N1 + nl) * 32 + quad * 8);
                #pragma unroll
                for (int j = 0; j < 8; ++j) hv[j] = hv[j] * hrd;
                a[2 + sI * 2 + hf] = hv;
            }
        }

        floatx4 acc[4];
        #pragma unroll
        for (int dt = 0; dt < 4; ++dt) {
            floatx4 z = {bv[dt], bv[dt], bv[dt], bv[dt]};
            acc[dt] = z;
        }
        #pragma unroll
        for (int t = 0; t < 8; ++t) {
            #pragma unroll
            for (int dt = 0; dt < 4; ++dt) {
                half8 bf = *(const half8*)(wf + (((dt * 8 + t) * 64 + lane) << 3));
                acc[dt] = __builtin_amdgcn_mfma_f32_16x16x32_f16(
                    a[t], bf, acc[dt], 0, 0, 0);
            }
        }

        #pragma unroll
        for (int dt = 0; dt < 4; ++dt)
            #pragma unroll
            for (int r = 0; r < 4; ++r) {
                int nn = n0 + quad * 4 + r;
                if (nn < N)
                    out[(size_t)nn * DIM + dt * 16 + col] =
                        fmaxf(acc[dt][r], 0.f);
            }
    }
}

extern "C" void kernel_launch(void* const* d_in, const int* in_sizes, int n_in,
                              void* d_out, int out_size, void* d_ws, size_t ws_size,
                              hipStream_t stream) {
    const float* x  = (const float*)d_in[0];
    const int*   ei = (const int*)d_in[1];
    const float* W  = (const float*)d_in[2];
    const float* b  = (const float*)d_in[3];
    float* out = (float*)d_out;

    const int N = in_sizes[0] / DIM;
    const int E = in_sizes[1] / 2;
    const int* row = ei;
    const int* col = ei + E;

    const int nbins = (N + 255) >> BIN_SHIFT;
    const int nbE = (E + 4095) / 4096;    // edge blocks (<=512 assumed)
    int sbps = (N + 15) / 16;             // blocks per superslab (16 nodes/blk)
    sbps = (sbps + 3) & ~3;               // x4 for the swizzle bijection
    const size_t SLABSZ = (size_t)2 * (N + 1) * 32;   // halves per buffer

    int* staging = (int*)d_ws;                            // 512*BCAP (packed)
    float* dinv  = (float*)(staging + (size_t)512 * BCAP);
    float* rdinv = dinv + N;
    _Float16* wf  = (_Float16*)(rdinv + N);               // 16384 halves
    _Float16* x16 = wf + 16384;                           // (N+16)*64
    _Float16* v0 = x16 + (size_t)(N + 16) * 64;
    _Float16* v1 = v0 + SLABSZ;
    _Float16* v3 = v1 + SLABSZ;
    _Float16* v7 = v3 + SLABSZ;
    _Float16* T1 = v7 + SLABSZ;
    _Float16* T2 = T1 + SLABSZ;
    int* deg = (int*)(T2 + SLABSZ);       // N
    int* ptr = deg + N;                   // N+1
    int* bs  = ptr + N + 1;               // <=1024
    int* bin_cursor = bs + 1024;          // 512
    int* srcs = bin_cursor + 512;         // E + 4N + 64 tail pad
    int* blockhist = srcs + (size_t)E + 4 * (size_t)N + 64;  // 512*512
    int* offs_g = blockhist + (size_t)512 * 512;             // 512*512

    // --- binning: hist -> per-bin scan over blocks -> atomic-free scatter ---
    hist_kernel<<<nbE, 256, 0, stream>>>(col, blockhist, E);
    scan_hist_kernel<<<512, 256, 0, stream>>>(blockhist, offs_g,
                                              bin_cursor, nbE);
    scatter_edges_kernel<<<nbE, 256, 0, stream>>>(row, col, offs_g,
                                                  staging, E);
    // --- per-bin degree + dinv/rdinv + padded chunk sums ---
    count_deg_bins_kernel<<<nbins, 256, 0, stream>>>(staging, bin_cursor,
                                                     deg, dinv, rdinv, bs, N);
    // --- scan of chunk sums, then per-chunk prefix -> ptr ---
    scan_block_sums_kernel<<<1, 1024, 0, stream>>>(bs, nbins);
    scan_chunks_kernel<<<nbins, 256, 0, stream>>>(deg, bs, ptr, N);
    // --- CSC fill from bins (self-edge + edges + dummy pads + tail pad) ---
    fill_bins_kernel<<<nbins, 256, 0, stream>>>(staging, bin_cursor, ptr,
                                                srcs, N, N);
    // --- fragment-ordered folded weights ---
    make_wfrag_kernel<<<64, 256, 0, stream>>>(W, wf);
    // --- v0 (superslab-major) + x16 + dummy-row zeroing ---
    scale_init_slab_kernel<<<(N * 16 + 96 + 255) / 256, 256, 0, stream>>>(
        x, dinv, v0, x16, v1, v3, v7, T1, T2, N);

    // --- persistent cooperative spmv chain (7 passes, 1 dispatch) ---
    int nvb = 2 * sbps;
    int grid = 1536;                      // 6 blocks/CU, multiple of 8
    void* args[] = {(void*)&ptr, (void*)&srcs, (void*)&dinv,
                    (void*)&v0, (void*)&v1, (void*)&v3, (void*)&v7,
                    (void*)&T1, (void*)&T2,
                    (void*)&N, (void*)&sbps, (void*)&nvb};
    hipLaunchCooperativeKernel((void*)spmv_chain_kernel, dim3(grid),
                               dim3(256), args, 0, stream);

    // --- combine (MFMA, fragment-table B, direct A loads, no LDS) ---
    combine_mfma_kernel<<<1024, 256, 0, stream>>>(x16, v1, v3, v7, rdinv,
                                                  wf, b, out, N);
}

// Round 20
// 403.052 us; speedup vs baseline: 4.3034x; 4.3034x over previous
//
#include <hip/hip_runtime.h>

#define DIM 64
#define BIN_SHIFT 8          // 256 nodes per bin
#define BCAP 5120            // staging capacity per bin (entries)

typedef __attribute__((ext_vector_type(8))) _Float16 half8;
typedef __attribute__((ext_vector_type(4))) _Float16 half4;
typedef __attribute__((ext_vector_type(4))) float floatx4;

// ---------------------------------------------------------------------------
// Binning pass A: per-block 512-bin histogram of col>>8 -> blockhist.
// ---------------------------------------------------------------------------
__launch_bounds__(256)
__global__ void hist_kernel(const int* __restrict__ col,
                            int* __restrict__ blockhist, int E) {
    __shared__ int hist[512];
    int tid = threadIdx.x;
    for (int i = tid; i < 512; i += 256) hist[i] = 0;
    __syncthreads();
    int e0 = blockIdx.x * 4096;
    #pragma unroll
    for (int k = 0; k < 16; ++k) {
        int e = e0 + tid + k * 256;
        if (e < E) atomicAdd(&hist[col[e] >> BIN_SHIFT], 1);
    }
    __syncthreads();
    for (int i = tid; i < 512; i += 256)
        blockhist[(size_t)blockIdx.x * 512 + i] = hist[i];
}

// ---------------------------------------------------------------------------
// Binning pass B: one block per bin; exclusive scan of blockhist over the
// edge-blocks -> per-(block,bin) base offsets; bin totals -> bin_cursor.
// ---------------------------------------------------------------------------
__global__ void scan_hist_kernel(const int* __restrict__ blockhist,
                                 int* __restrict__ offs_g,
                                 int* __restrict__ bin_cursor, int nb) {
    __shared__ int s[256];
    int bin = blockIdx.x, t = threadIdx.x;
    int h0 = (2 * t < nb)     ? blockhist[(size_t)(2 * t) * 512 + bin]     : 0;
    int h1 = (2 * t + 1 < nb) ? blockhist[(size_t)(2 * t + 1) * 512 + bin] : 0;
    int ps = h0 + h1;
    s[t] = ps;
    __syncthreads();
    for (int d = 1; d < 256; d <<= 1) {
        int v = (t >= d) ? s[t - d] : 0;
        __syncthreads();
        s[t] += v;
        __syncthreads();
    }
    int ex = s[t] - ps;
    if (2 * t < nb)     offs_g[(size_t)(2 * t) * 512 + bin] = ex;
    if (2 * t + 1 < nb) offs_g[(size_t)(2 * t + 1) * 512 + bin] = ex + h0;
    if (t == 255) bin_cursor[bin] = s[255];
}

// ---------------------------------------------------------------------------
// Binning pass C: in-block counting sort by bin in LDS; deterministic bases
// from offs_g (no global atomics). Bin-sorted readout -> contiguous store
// runs per bin segment.
// ---------------------------------------------------------------------------
__launch_bounds__(256)
__global__ void scatter_edges_kernel(const int* __restrict__ row,
                                     const int* __restrict__ col,
                                     const int* __restrict__ offs_g,
                                     int2* __restrict__ staging, int E) {
    __shared__ int hist[512];
    __shared__ int offs[512];
    __shared__ int base[512];
    __shared__ int s[256];
    __shared__ int2 buf[4096];
    int tid = threadIdx.x;
    for (int i = tid; i < 512; i += 256) hist[i] = 0;
    __syncthreads();
    int e0 = blockIdx.x * 4096;
    int c[16], r[16];
    #pragma unroll
    for (int k = 0; k < 16; ++k) {
        int e = e0 + tid + k * 256;
        c[k] = (e < E) ? col[e] : -1;
        r[k] = (e < E) ? row[e] : 0;
        if (c[k] >= 0) atomicAdd(&hist[c[k] >> BIN_SHIFT], 1);
    }
    __syncthreads();
    // exclusive scan of hist[512] via pair-sums + Hillis-Steele over 256
    int h0 = hist[2 * tid], h1 = hist[2 * tid + 1];
    int ps = h0 + h1;
    s[tid] = ps;
    __syncthreads();
    for (int d = 1; d < 256; d <<= 1) {
        int v = (tid >= d) ? s[tid - d] : 0;
        __syncthreads();
        s[tid] += v;
        __syncthreads();
    }
    int ex = s[tid] - ps;
    offs[2 * tid] = ex;
    offs[2 * tid + 1] = ex + h0;
    __syncthreads();
    // deterministic per-(block,bin) base; reset hist as scatter cursor
    for (int i = tid; i < 512; i += 256) {
        base[i] = offs_g[(size_t)blockIdx.x * 512 + i];
        hist[i] = 0;
    }
    __syncthreads();
    // scatter into bin-sorted LDS buffer
    #pragma unroll
    for (int k = 0; k < 16; ++k) {
        if (c[k] >= 0) {
            int b = c[k] >> BIN_SHIFT;
            int pos = offs[b] + atomicAdd(&hist[b], 1);
            buf[pos] = make_int2(r[k], c[k]);
        }
    }
    __syncthreads();
    // linear readout: adjacent lanes -> adjacent buf -> contiguous store runs
    int count = (e0 + 4096 <= E) ? 4096 : (E > e0 ? E - e0 : 0);
    for (int i = tid; i < count; i += 256) {
        int2 rc = buf[i];
        int b = rc.y >> BIN_SHIFT;
        staging[(size_t)b * BCAP + base[b] + (i - offs[b])] = rc;
    }
}

// ---------------------------------------------------------------------------
// Per-bin degree count + dinv/rdinv + padded chunk sum bs[b].
// pdeg = (deg+1+3)&~3  (self-edge included, pad to groups of 4).
// ---------------------------------------------------------------------------
__launch_bounds__(256)
__global__ void count_deg_bins_kernel(const int2* __restrict__ staging,
                                      const int* __restrict__ bin_cursor,
                                      int* __restrict__ deg,
                                      float* __restrict__ dinv,
                                      float* __restrict__ rdinv,
                                      int* __restrict__ bs, int N) {
    __shared__ int hist[256];
    __shared__ int red[256];
    int b = blockIdx.x;
    int tid = threadIdx.x;
    hist[tid] = 0;
    __syncthreads();
    int cnt = bin_cursor[b];
    for (int i = tid; i < cnt; i += 256)
        atomicAdd(&hist[staging[(size_t)b * BCAP + i].y & 255], 1);
    __syncthreads();
    int n = (b << BIN_SHIFT) + tid;
    int pdeg = 0;
    if (n < N) {
        int dg = hist[tid];
        deg[n] = dg;
        float d = (float)dg + 1.0f;
        dinv[n] = rsqrtf(d);
        rdinv[n] = sqrtf(d);
        pdeg = (dg + 1 + 3) & ~3;
    }
    red[tid] = pdeg;
    __syncthreads();
    for (int d = 128; d > 0; d >>= 1) {
        if (tid < d) red[tid] += red[tid + d];
        __syncthreads();
    }
    if (tid == 0) bs[b] = red[0];
}

__global__ void scan_block_sums_kernel(int* __restrict__ bs, int nb) {
    __shared__ int s[1024];
    int t = threadIdx.x;
    s[t] = (t < nb) ? bs[t] : 0;
    __syncthreads();
    for (int d = 1; d < 1024; d <<= 1) {
        int v = (t >= d) ? s[t - d] : 0;
        __syncthreads();
        s[t] += v;
        __syncthreads();
    }
    if (t < nb) bs[t] = (t == 0) ? 0 : s[t - 1];
}

__global__ void scan_chunks_kernel(const int* __restrict__ deg,
                                   const int* __restrict__ bs,
                                   int* __restrict__ ptr, int N) {
    __shared__ int s[256];
    int b = blockIdx.x, t = threadIdx.x;
    int i = b * 256 + t;
    int v = (i < N) ? ((deg[i] + 1 + 3) & ~3) : 0;
    s[t] = v;
    __syncthreads();
    for (int d = 1; d < 256; d <<= 1) {
        int u = (t >= d) ? s[t - d] : 0;
        __syncthreads();
        s[t] += u;
        __syncthreads();
    }
    if (i < N) {
        int p = bs[b] + s[t] - v;
        ptr[i] = p;
        if (i == N - 1) ptr[N] = p + v;
    }
}

// ---------------------------------------------------------------------------
// CSC fill from bins: one block per bin; LDS cursors. Self-edge, in-edges,
// dummy-N padding to x4; 64-int tail pad in last block.
// ---------------------------------------------------------------------------
__launch_bounds__(256)
__global__ void fill_bins_kernel(const int2* __restrict__ staging,
                                 const int* __restrict__ bin_cursor,
                                 const int* __restrict__ ptr,
                                 int* __restrict__ srcs, int N, int dummy) {
    __shared__ int cur[256];
    int b = blockIdx.x;
    int tid = threadIdx.x;
    int n = (b << BIN_SHIFT) + tid;
    if (n < N) {
        int p = ptr[n];
        srcs[p] = n;           // self-edge
        cur[tid] = p + 1;
    } else cur[tid] = 0;
    if (b == gridDim.x - 1 && tid < 64)
        srcs[ptr[N] + tid] = dummy;      // tail pad: valid (zero) row ids
    __syncthreads();
    int cnt = bin_cursor[b];
    for (int i = tid; i < cnt; i += 256) {
        int2 rc = staging[(size_t)b * BCAP + i];
        int pos = atomicAdd(&cur[rc.y & 255], 1);
        srcs[pos] = rc.x;
    }
    __syncthreads();
    if (n < N) {
        int e = cur[tid];            // == ptr[n] + 1 + deg[n]
        int stop = ptr[n + 1];
        for (; e < stop; ++e) srcs[e] = dummy;
    }
}

// ---------------------------------------------------------------------------
// scale_init: v0 (superslab-major fp16 = dinv*x), x16 (row-major fp16), and
// dummy-row zeroing for all 6 superslab buffers (tail threads).
// Superslab S = d>>5 (32 halves = 64B per row), row n at (S*(N+1)+n)*32.
// ---------------------------------------------------------------------------
__global__ void scale_init_slab_kernel(const float* __restrict__ x,
                                       const float* __restrict__ dinv,
                                       _Float16* __restrict__ v0,
                                       _Float16* __restrict__ x16,
                                       _Float16* __restrict__ v1,
                                       _Float16* __restrict__ v3,
                                       _Float16* __restrict__ v7,
                                       _Float16* __restrict__ T1,
                                       _Float16* __restrict__ T2, int N) {
    int t = blockIdx.x * blockDim.x + threadIdx.x;
    if (t < N * 16) {
        int n = t >> 4, d4 = (t & 15) * 4;
        float d = dinv[n];
        float4 a = *(const float4*)(x + (size_t)n * DIM + d4);
        half4 hx;
        hx.x = (_Float16)a.x; hx.y = (_Float16)a.y;
        hx.z = (_Float16)a.z; hx.w = (_Float16)a.w;
        *(half4*)(x16 + (size_t)n * DIM + d4) = hx;
        half4 hv;
        hv.x = (_Float16)(a.x * d); hv.y = (_Float16)(a.y * d);
        hv.z = (_Float16)(a.z * d); hv.w = (_Float16)(a.w * d);
        int S = d4 >> 5, off = d4 & 31;
        *(half4*)(v0 + ((size_t)S * (N + 1) + n) * 32 + off) = hv;
    } else {
        int extra = t - N * 16;      // 96 half4 slots: 6 buffers x 64 halves
        if (extra < 96) {
            _Float16* bufs[6] = {v0, v1, v3, v7, T1, T2};
            int bf = extra >> 4;
            int r = (extra & 15) * 4;
            int S = r >> 5, off = r & 31;
            half4 z = {(_Float16)0.f, (_Float16)0.f,
                       (_Float16)0.f, (_Float16)0.f};
            *(half4*)(bufs[bf] + ((size_t)S * (N + 1) + N) * 32 + off) = z;
        }
    }
}

// ---------------------------------------------------------------------------
// Superslab-major propagate (R13 geometry, measured local optimum): wave =
// 4 nodes x 4 slots x 4 chunks of 16B over 64B rows (full line utilization,
// 2 lines/edge = minimum). Straight-line 6-group preload, x4 padding,
// 2-step reduce (xor 4,8). XCD-quad pinning: superslab S = (blockIdx&7)>>2.
// Separate dispatches per pass (R19 proved grid.sync costs 6x: per-XCD L2
// invalidation + serial per-wave vb loops kill the latency hiding that
// block churn provides for free).
// ---------------------------------------------------------------------------
__launch_bounds__(256)
__global__ void spmv_slab_kernel(const int* __restrict__ ptr,
                                 const int* __restrict__ srcs,
                                 const float* __restrict__ dinv,
                                 const _Float16* __restrict__ vin,
                                 _Float16* __restrict__ vout,
                                 int N, int bps) {
    int b = blockIdx.x;
    int S   = (b & 7) >> 2;                  // XCD quad -> superslab
    int blk = ((b >> 3) << 2) | (b & 3);     // index within superslab
    if (blk >= bps) return;
    const _Float16* vi = vin + (size_t)S * (N + 1) * 32;
    _Float16* vo = vout + (size_t)S * (N + 1) * 32;
    int tid = threadIdx.x;
    int lane = tid & 63;
    int nq = (lane >> 4) & 3;     // node 0..3 within wave
    int e  = (lane >> 2) & 3;     // edge slot 0..3
    int hc = (lane & 3) << 3;     // 16B chunk of the 64B row (half offset)
    int n = blk * 16 + (tid >> 6) * 4 + nq;
    bool valid = n < N;

    // phase 0: independent per-node loads
    int beg = valid ? ptr[n] : 0;
    int end = valid ? ptr[n + 1] : 0;
    float d = valid ? dinv[n] : 0.f;

    // phase 1: group indices 0..5 preloaded (6 srcs loads in flight)
    int s0 = srcs[beg + e];
    int s1 = srcs[beg + 4 + e];
    int s2 = srcs[beg + 8 + e];
    int s3 = srcs[beg + 12 + e];
    int s4 = srcs[beg + 16 + e];
    int s5 = srcs[beg + 20 + e];

    // phase 2: unconditional group 0..3 gathers (4 in flight)
    half8 h0 = *(const half8*)(vi + ((size_t)s0 << 5) + hc);
    half8 h1 = *(const half8*)(vi + ((size_t)s1 << 5) + hc);
    half8 h2 = *(const half8*)(vi + ((size_t)s2 << 5) + hc);
    half8 h3 = *(const half8*)(vi + ((size_t)s3 << 5) + hc);

    half8 z;
    #pragma unroll
    for (int k = 0; k < 8; ++k) z[k] = (_Float16)0.f;

    bool m1 = (beg + 8  <= end);
    bool m2 = (beg + 12 <= end);
    bool m3 = (beg + 16 <= end);
    half8 t01 = h0 + (m1 ? h1 : z);            // fp16 pk_add tree (depth 2)
    half8 t23 = (m2 ? h2 : z) + (m3 ? h3 : z);
    half8 g = t01 + t23;

    float a[8];
    #pragma unroll
    for (int k = 0; k < 8; ++k) a[k] = (float)g[k];

    // groups 4/5 (66% / 25% of nodes), then rare loop (6%)
    if (beg + 20 <= end) {
        half8 h4 = *(const half8*)(vi + ((size_t)s4 << 5) + hc);
        #pragma unroll
        for (int k = 0; k < 8; ++k) a[k] += (float)h4[k];
        if (beg + 24 <= end) {
            half8 h5 = *(const half8*)(vi + ((size_t)s5 << 5) + hc);
            #pragma unroll
            for (int k = 0; k < 8; ++k) a[k] += (float)h5[k];
            for (int j = beg + 24; j + 4 <= end; j += 4) {
                int s = srcs[j + e];
                half8 hx = *(const half8*)(vi + ((size_t)s << 5) + hc);
                #pragma unroll
                for (int k = 0; k < 8; ++k) a[k] += (float)hx[k];
            }
        }
    }

    // reduce across the 4 edge slots (lane bits 2,3): 2 steps
    #pragma unroll
    for (int k = 0; k < 8; ++k) {
        a[k] += __shfl_xor(a[k], 4);
        a[k] += __shfl_xor(a[k], 8);
    }
    if (e == 0 && valid) {
        float dd = d * d;
        half8 r;
        #pragma unroll
        for (int k = 0; k < 8; ++k)
            r[k] = (_Float16)(dd * a[k]);
        *(half8*)(vo + ((size_t)n << 5) + hc) = r;
    }
}

// ---------------------------------------------------------------------------
// make_wfrag: folded effective weights, fp16, MFMA B-fragment order
// wf[((dt*8 + t)*64 + lane)*8 + j]  (lane = quad*16+col).
// Fold: cat@W = x@W3 + p1@(W0-W3+W4) + p3@(W1-W4+W5) + p7@(W2-W5)
// ---------------------------------------------------------------------------
__global__ void make_wfrag_kernel(const float* __restrict__ W,
                                  _Float16* __restrict__ wf) {
    int idx = blockIdx.x * blockDim.x + threadIdx.x;   // 16384
    if (idx < 16384) {
        int j = idx & 7;
        int lane = (idx >> 3) & 63;
        int t = (idx >> 9) & 7;
        int dt = idx >> 12;
        int col = lane & 15, quad = lane >> 4;
        int d = dt * 16 + col;
        int kk = t * 32 + quad * 8 + j;
        int src = kk >> 6, k = kk & 63;
        float v;
        if (src == 0)      v = W[(3 * 64 + k) * 64 + d];
        else if (src == 1) v = W[(0 * 64 + k) * 64 + d]
                             - W[(3 * 64 + k) * 64 + d]
                             + W[(4 * 64 + k) * 64 + d];
        else if (src == 2) v = W[(1 * 64 + k) * 64 + d]
                             - W[(4 * 64 + k) * 64 + d]
                             + W[(5 * 64 + k) * 64 + d];
        else               v = W[(2 * 64 + k) * 64 + d]
                             - W[(5 * 64 + k) * 64 + d];
        wf[idx] = (_Float16)v;
    }
}

// ---------------------------------------------------------------------------
// MFMA combine: no LDS, no syncthreads. A-fragments direct from global;
// B-fragments from the 32 KB fragment-ordered wf table. One wave = one
// 16-node group, all 64 output dims (32 mfma). Superslab: S=d0>>5, off=d0&31.
// ---------------------------------------------------------------------------
__launch_bounds__(256)
__global__ void combine_mfma_kernel(const _Float16* __restrict__ x16,
                                    const _Float16* __restrict__ v1,
                                    const _Float16* __restrict__ v3,
                                    const _Float16* __restrict__ v7,
                                    const float* __restrict__ rdinv,
                                    const _Float16* __restrict__ wf,
                                    const float* __restrict__ bias,
                                    float* __restrict__ out, int N) {
    int tid = threadIdx.x;
    int lane = tid & 63, w = tid >> 6;
    int quad = lane >> 4, col = lane & 15;

    float bv[4];
    #pragma unroll
    for (int dt = 0; dt < 4; ++dt) bv[dt] = bias[dt * 16 + col];

    int bps = (N + 15) / 16;
    size_t N1 = (size_t)N + 1;
    for (int g = blockIdx.x * 4 + w; g < bps; g += gridDim.x * 4) {
        int n0 = g * 16;
        int n = n0 + col;
        int nl = (n < N) ? n : 0;
        _Float16 hrd = (_Float16)rdinv[nl];

        half8 a[8];
        a[0] = *(const half8*)(x16 + (size_t)nl * DIM + quad * 8);
        a[1] = *(const half8*)(x16 + (size_t)nl * DIM + 32 + quad * 8);
        const _Float16* vs[3] = {v1, v3, v7};
        #pragma unroll
        for (int sI = 0; sI < 3; ++sI) {
            #pragma unroll
            for (int hf = 0; hf < 2; ++hf) {
                // d0 = hf*32 + quad*8  ->  superslab S = hf, offset quad*8
                half8 hv = *(const half8*)(vs[sI] + ((size_t)hf * N1 + nl) * 32 + quad * 8);
                #pragma unroll
                for (int j = 0; j < 8; ++j) hv[j] = hv[j] * hrd;
                a[2 + sI * 2 + hf] = hv;
            }
        }

        floatx4 acc[4];
        #pragma unroll
        for (int dt = 0; dt < 4; ++dt) {
            floatx4 z = {bv[dt], bv[dt], bv[dt], bv[dt]};
            acc[dt] = z;
        }
        #pragma unroll
        for (int t = 0; t < 8; ++t) {
            #pragma unroll
            for (int dt = 0; dt < 4; ++dt) {
                half8 bf = *(const half8*)(wf + (((dt * 8 + t) * 64 + lane) << 3));
                acc[dt] = __builtin_amdgcn_mfma_f32_16x16x32_f16(
                    a[t], bf, acc[dt], 0, 0, 0);
            }
        }

        #pragma unroll
        for (int dt = 0; dt < 4; ++dt)
            #pragma unroll
            for (int r = 0; r < 4; ++r) {
                int nn = n0 + quad * 4 + r;
                if (nn < N)
                    out[(size_t)nn * DIM + dt * 16 + col] =
                        fmaxf(acc[dt][r], 0.f);
            }
    }
}

extern "C" void kernel_launch(void* const* d_in, const int* in_sizes, int n_in,
                              void* d_out, int out_size, void* d_ws, size_t ws_size,
                              hipStream_t stream) {
    const float* x  = (const float*)d_in[0];
    const int*   ei = (const int*)d_in[1];
    const float* W  = (const float*)d_in[2];
    const float* b  = (const float*)d_in[3];
    float* out = (float*)d_out;

    const int N = in_sizes[0] / DIM;
    const int E = in_sizes[1] / 2;
    const int* row = ei;
    const int* col = ei + E;

    const int nbins = (N + 255) >> BIN_SHIFT;
    const int nbE = (E + 4095) / 4096;    // edge blocks (<=512 assumed)
    int sbps = (N + 15) / 16;             // blocks per superslab (16 nodes/blk)
    sbps = (sbps + 3) & ~3;               // x4 for the swizzle bijection
    const size_t SLABSZ = (size_t)2 * (N + 1) * 32;   // halves per buffer

    int2* staging = (int2*)d_ws;                          // 512*BCAP
    float* dinv  = (float*)(staging + (size_t)512 * BCAP);
    float* rdinv = dinv + N;
    _Float16* wf  = (_Float16*)(rdinv + N);               // 16384 halves
    _Float16* x16 = wf + 16384;                           // (N+16)*64
    _Float16* v0 = x16 + (size_t)(N + 16) * 64;
    _Float16* v1 = v0 + SLABSZ;
    _Float16* v3 = v1 + SLABSZ;
    _Float16* v7 = v3 + SLABSZ;
    _Float16* T1 = v7 + SLABSZ;
    _Float16* T2 = T1 + SLABSZ;
    int* deg = (int*)(T2 + SLABSZ);       // N
    int* ptr = deg + N;                   // N+1
    int* bs  = ptr + N + 1;               // <=1024
    int* bin_cursor = bs + 1024;          // 512
    int* srcs = bin_cursor + 512;         // E + 4N + 64 tail pad
    int* blockhist = srcs + (size_t)E + 4 * (size_t)N + 64;  // 512*512
    int* offs_g = blockhist + (size_t)512 * 512;             // 512*512

    // --- binning: hist -> per-bin scan over blocks -> atomic-free scatter ---
    hist_kernel<<<nbE, 256, 0, stream>>>(col, blockhist, E);
    scan_hist_kernel<<<512, 256, 0, stream>>>(blockhist, offs_g,
                                              bin_cursor, nbE);
    scatter_edges_kernel<<<nbE, 256, 0, stream>>>(row, col, offs_g,
                                                  staging, E);
    // --- per-bin degree + dinv/rdinv + padded chunk sums ---
    count_deg_bins_kernel<<<nbins, 256, 0, stream>>>(staging, bin_cursor,
                                                     deg, dinv, rdinv, bs, N);
    // --- scan of chunk sums, then per-chunk prefix -> ptr ---
    scan_block_sums_kernel<<<1, 1024, 0, stream>>>(bs, nbins);
    scan_chunks_kernel<<<nbins, 256, 0, stream>>>(deg, bs, ptr, N);
    // --- CSC fill from bins (self-edge + edges + dummy pads + tail pad) ---
    fill_bins_kernel<<<nbins, 256, 0, stream>>>(staging, bin_cursor, ptr,
                                                srcs, N, N);
    // --- fragment-ordered folded weights ---
    make_wfrag_kernel<<<64, 256, 0, stream>>>(W, wf);
    // --- v0 (superslab-major) + x16 + dummy-row zeroing ---
    scale_init_slab_kernel<<<(N * 16 + 96 + 255) / 256, 256, 0, stream>>>(
        x, dinv, v0, x16, v1, v3, v7, T1, T2, N);

    auto prop = [&](const _Float16* src, _Float16* dst) {
        spmv_slab_kernel<<<2 * sbps, 256, 0, stream>>>(ptr, srcs, dinv,
                                                       src, dst, N, sbps);
    };
    prop(v0, v1);   // A^1
    prop(v1, T1);   // A^2
    prop(T1, v3);   // A^3
    prop(v3, T1);   // A^4
    prop(T1, T2);   // A^5
    prop(T2, T1);   // A^6
    prop(T1, v7);   // A^7

    // --- combine (MFMA, fragment-table B, direct A loads, no LDS) ---
    combine_mfma_kernel<<<1024, 256, 0, stream>>>(x16, v1, v3, v7, rdinv,
                                                  wf, b, out, N);
}

// Round 22
// 310.070 us; speedup vs baseline: 5.5939x; 1.2999x over previous
//
#include <hip/hip_runtime.h>

#define DIM 64
#define BIN_SHIFT 8          // 256 nodes per bin
#define BCAP 5120            // staging capacity per bin (entries)

typedef __attribute__((ext_vector_type(8))) _Float16 half8;
typedef __attribute__((ext_vector_type(4))) _Float16 half4;
typedef __attribute__((ext_vector_type(4))) float floatx4;
typedef __attribute__((ext_vector_type(2))) float floatx2;

// ---------------------------------------------------------------------------
// Binning pass A: per-block 512-bin histogram of col>>8 -> blockhist.
// ---------------------------------------------------------------------------
__launch_bounds__(256)
__global__ void hist_kernel(const int* __restrict__ col,
                            int* __restrict__ blockhist, int E) {
    __shared__ int hist[512];
    int tid = threadIdx.x;
    for (int i = tid; i < 512; i += 256) hist[i] = 0;
    __syncthreads();
    int e0 = blockIdx.x * 4096;
    #pragma unroll
    for (int k = 0; k < 16; ++k) {
        int e = e0 + tid + k * 256;
        if (e < E) atomicAdd(&hist[col[e] >> BIN_SHIFT], 1);
    }
    __syncthreads();
    for (int i = tid; i < 512; i += 256)
        blockhist[(size_t)blockIdx.x * 512 + i] = hist[i];
}

// ---------------------------------------------------------------------------
// Binning pass B: one block per bin; exclusive scan of blockhist over the
// edge-blocks -> per-(block,bin) base offsets; bin totals -> bin_cursor.
// ---------------------------------------------------------------------------
__global__ void scan_hist_kernel(const int* __restrict__ blockhist,
                                 int* __restrict__ offs_g,
                                 int* __restrict__ bin_cursor, int nb) {
    __shared__ int s[256];
    int bin = blockIdx.x, t = threadIdx.x;
    int h0 = (2 * t < nb)     ? blockhist[(size_t)(2 * t) * 512 + bin]     : 0;
    int h1 = (2 * t + 1 < nb) ? blockhist[(size_t)(2 * t + 1) * 512 + bin] : 0;
    int ps = h0 + h1;
    s[t] = ps;
    __syncthreads();
    for (int d = 1; d < 256; d <<= 1) {
        int v = (t >= d) ? s[t - d] : 0;
        __syncthreads();
        s[t] += v;
        __syncthreads();
    }
    int ex = s[t] - ps;
    if (2 * t < nb)     offs_g[(size_t)(2 * t) * 512 + bin] = ex;
    if (2 * t + 1 < nb) offs_g[(size_t)(2 * t + 1) * 512 + bin] = ex + h0;
    if (t == 255) bin_cursor[bin] = s[255];
}

// ---------------------------------------------------------------------------
// Binning pass C: in-block counting sort by bin in LDS; deterministic bases
// from offs_g (no global atomics). Bin-sorted readout -> contiguous store
// runs per bin segment.
// ---------------------------------------------------------------------------
__launch_bounds__(256)
__global__ void scatter_edges_kernel(const int* __restrict__ row,
                                     const int* __restrict__ col,
                                     const int* __restrict__ offs_g,
                                     int2* __restrict__ staging, int E) {
    __shared__ int hist[512];
    __shared__ int offs[512];
    __shared__ int base[512];
    __shared__ int s[256];
    __shared__ int2 buf[4096];
    int tid = threadIdx.x;
    for (int i = tid; i < 512; i += 256) hist[i] = 0;
    __syncthreads();
    int e0 = blockIdx.x * 4096;
    int c[16], r[16];
    #pragma unroll
    for (int k = 0; k < 16; ++k) {
        int e = e0 + tid + k * 256;
        c[k] = (e < E) ? col[e] : -1;
        r[k] = (e < E) ? row[e] : 0;
        if (c[k] >= 0) atomicAdd(&hist[c[k] >> BIN_SHIFT], 1);
    }
    __syncthreads();
    int h0 = hist[2 * tid], h1 = hist[2 * tid + 1];
    int ps = h0 + h1;
    s[tid] = ps;
    __syncthreads();
    for (int d = 1; d < 256; d <<= 1) {
        int v = (tid >= d) ? s[tid - d] : 0;
        __syncthreads();
        s[tid] += v;
        __syncthreads();
    }
    int ex = s[tid] - ps;
    offs[2 * tid] = ex;
    offs[2 * tid + 1] = ex + h0;
    __syncthreads();
    for (int i = tid; i < 512; i += 256) {
        base[i] = offs_g[(size_t)blockIdx.x * 512 + i];
        hist[i] = 0;
    }
    __syncthreads();
    #pragma unroll
    for (int k = 0; k < 16; ++k) {
        if (c[k] >= 0) {
            int b = c[k] >> BIN_SHIFT;
            int pos = offs[b] + atomicAdd(&hist[b], 1);
            buf[pos] = make_int2(r[k], c[k]);
        }
    }
    __syncthreads();
    int count = (e0 + 4096 <= E) ? 4096 : (E > e0 ? E - e0 : 0);
    for (int i = tid; i < count; i += 256) {
        int2 rc = buf[i];
        int b = rc.y >> BIN_SHIFT;
        staging[(size_t)b * BCAP + base[b] + (i - offs[b])] = rc;
    }
}

// ---------------------------------------------------------------------------
// Per-bin degree count + dinv/rdinv + padded chunk sum bs[b].
// pdeg = (deg+1+3)&~3  (self-edge included, pad to groups of 4).
// ---------------------------------------------------------------------------
__launch_bounds__(256)
__global__ void count_deg_bins_kernel(const int2* __restrict__ staging,
                                      const int* __restrict__ bin_cursor,
                                      int* __restrict__ deg,
                                      float* __restrict__ dinv,
                                      float* __restrict__ rdinv,
                                      int* __restrict__ bs, int N) {
    __shared__ int hist[256];
    __shared__ int red[256];
    int b = blockIdx.x;
    int tid = threadIdx.x;
    hist[tid] = 0;
    __syncthreads();
    int cnt = bin_cursor[b];
    for (int i = tid; i < cnt; i += 256)
        atomicAdd(&hist[staging[(size_t)b * BCAP + i].y & 255], 1);
    __syncthreads();
    int n = (b << BIN_SHIFT) + tid;
    int pdeg = 0;
    if (n < N) {
        int dg = hist[tid];
        deg[n] = dg;
        float d = (float)dg + 1.0f;
        dinv[n] = rsqrtf(d);
        rdinv[n] = sqrtf(d);
        pdeg = (dg + 1 + 3) & ~3;
    }
    red[tid] = pdeg;
    __syncthreads();
    for (int d = 128; d > 0; d >>= 1) {
        if (tid < d) red[tid] += red[tid + d];
        __syncthreads();
    }
    if (tid == 0) bs[b] = red[0];
}

__global__ void scan_block_sums_kernel(int* __restrict__ bs, int nb) {
    __shared__ int s[1024];
    int t = threadIdx.x;
    s[t] = (t < nb) ? bs[t] : 0;
    __syncthreads();
    for (int d = 1; d < 1024; d <<= 1) {
        int v = (t >= d) ? s[t - d] : 0;
        __syncthreads();
        s[t] += v;
        __syncthreads();
    }
    if (t < nb) bs[t] = (t == 0) ? 0 : s[t - 1];
}

__global__ void scan_chunks_kernel(const int* __restrict__ deg,
                                   const int* __restrict__ bs,
                                   int* __restrict__ ptr, int N) {
    __shared__ int s[256];
    int b = blockIdx.x, t = threadIdx.x;
    int i = b * 256 + t;
    int v = (i < N) ? ((deg[i] + 1 + 3) & ~3) : 0;
    s[t] = v;
    __syncthreads();
    for (int d = 1; d < 256; d <<= 1) {
        int u = (t >= d) ? s[t - d] : 0;
        __syncthreads();
        s[t] += u;
        __syncthreads();
    }
    if (i < N) {
        int p = bs[b] + s[t] - v;
        ptr[i] = p;
        if (i == N - 1) ptr[N] = p + v;
    }
}

// ---------------------------------------------------------------------------
// CSC fill from bins: one block per bin; LDS cursors. Self-edge, in-edges,
// dummy-N padding to x4; 64-int tail pad in last block.
// ---------------------------------------------------------------------------
__launch_bounds__(256)
__global__ void fill_bins_kernel(const int2* __restrict__ staging,
                                 const int* __restrict__ bin_cursor,
                                 const int* __restrict__ ptr,
                                 int* __restrict__ srcs, int N, int dummy) {
    __shared__ int cur[256];
    int b = blockIdx.x;
    int tid = threadIdx.x;
    int n = (b << BIN_SHIFT) + tid;
    if (n < N) {
        int p = ptr[n];
        srcs[p] = n;           // self-edge
        cur[tid] = p + 1;
    } else cur[tid] = 0;
    if (b == gridDim.x - 1 && tid < 64)
        srcs[ptr[N] + tid] = dummy;      // tail pad: valid (zero) row ids
    __syncthreads();
    int cnt = bin_cursor[b];
    for (int i = tid; i < cnt; i += 256) {
        int2 rc = staging[(size_t)b * BCAP + i];
        int pos = atomicAdd(&cur[rc.y & 255], 1);
        srcs[pos] = rc.x;
    }
    __syncthreads();
    if (n < N) {
        int e = cur[tid];            // == ptr[n] + 1 + deg[n]
        int stop = ptr[n + 1];
        for (; e < stop; ++e) srcs[e] = dummy;
    }
}

// ---------------------------------------------------------------------------
// scale_init: v0 as FP8 e4m3 (row n = 64 bytes = all 64 dims, ONE cache
// line per node), x16 (row-major fp16), dummy-row-N zeroing for all 6 fp8
// buffers.
// ---------------------------------------------------------------------------
__global__ void scale_init_slab_kernel(const float* __restrict__ x,
                                       const float* __restrict__ dinv,
                                       unsigned char* __restrict__ v0,
                                       _Float16* __restrict__ x16,
                                       unsigned char* __restrict__ v1,
                                       unsigned char* __restrict__ v3,
                                       unsigned char* __restrict__ v7,
                                       unsigned char* __restrict__ T1,
                                       unsigned char* __restrict__ T2, int N) {
    int t = blockIdx.x * blockDim.x + threadIdx.x;
    if (t < N * 16) {
        int n = t >> 4, d4 = (t & 15) * 4;
        float d = dinv[n];
        float4 a = *(const float4*)(x + (size_t)n * DIM + d4);
        half4 hx;
        hx.x = (_Float16)a.x; hx.y = (_Float16)a.y;
        hx.z = (_Float16)a.z; hx.w = (_Float16)a.w;
        *(half4*)(x16 + (size_t)n * DIM + d4) = hx;
        int w = __builtin_amdgcn_cvt_pk_fp8_f32(a.x * d, a.y * d, 0, 0);
        w = __builtin_amdgcn_cvt_pk_fp8_f32(a.z * d, a.w * d, w, 1);
        *(int*)(v0 + (size_t)n * 64 + d4) = w;
    } else {
        int extra = t - N * 16;      // 96 int slots: 6 buffers x 64 bytes
        if (extra < 96) {
            unsigned char* bufs[6] = {v0, v1, v3, v7, T1, T2};
            unsigned char* buf = bufs[extra >> 4];
            int r = (extra & 15) * 4;
            *(int*)(buf + (size_t)N * 64 + r) = 0;
        }
    }
}

// ---------------------------------------------------------------------------
// fp8 row accumulate: 16 fp8 bytes -> 16 fp32 via HW cvt (vector result,
// indexed with [0]/[1]), masked fma.
// ---------------------------------------------------------------------------
__device__ __forceinline__
void acc_row(const unsigned char* __restrict__ p, float m, float* a) {
    uint4 q = *(const uint4*)p;
    floatx2 f;
    f = __builtin_amdgcn_cvt_pk_f32_fp8(q.x, 0);
    a[0] += m * f[0];  a[1] += m * f[1];
    f = __builtin_amdgcn_cvt_pk_f32_fp8(q.x, 1);
    a[2] += m * f[0];  a[3] += m * f[1];
    f = __builtin_amdgcn_cvt_pk_f32_fp8(q.y, 0);
    a[4] += m * f[0];  a[5] += m * f[1];
    f = __builtin_amdgcn_cvt_pk_f32_fp8(q.y, 1);
    a[6] += m * f[0];  a[7] += m * f[1];
    f = __builtin_amdgcn_cvt_pk_f32_fp8(q.z, 0);
    a[8] += m * f[0];  a[9] += m * f[1];
    f = __builtin_amdgcn_cvt_pk_f32_fp8(q.z, 1);
    a[10] += m * f[0]; a[11] += m * f[1];
    f = __builtin_amdgcn_cvt_pk_f32_fp8(q.w, 0);
    a[12] += m * f[0]; a[13] += m * f[1];
    f = __builtin_amdgcn_cvt_pk_f32_fp8(q.w, 1);
    a[14] += m * f[0]; a[15] += m * f[1];
}

// ---------------------------------------------------------------------------
// FP8 propagate: ONE 64B line per node row (all 64 dims). Line-touches per
// pass halve vs fp16 two-superslab (3.7M -> 1.86M) -- attacks the measured
// ~0.9 lines/cyc/CU L1 line-return ceiling every fp16 variant hit.
// Wave = 4 nodes x 4 slots x 4 chunks of 16B; straight-line 6-group preload,
// x4 padding, 2-step reduce (xor 4,8). Accumulate fp32, requantize to fp8.
// No superslab split -> half the waves, srcs/ptr read once.
// ---------------------------------------------------------------------------
__launch_bounds__(256)
__global__ void spmv_fp8_kernel(const int* __restrict__ ptr,
                                const int* __restrict__ srcs,
                                const float* __restrict__ dinv,
                                const unsigned char* __restrict__ vin,
                                unsigned char* __restrict__ vout, int N) {
    int blk = blockIdx.x;
    int tid = threadIdx.x;
    int lane = tid & 63;
    int nq = (lane >> 4) & 3;     // node 0..3 within wave
    int e  = (lane >> 2) & 3;     // edge slot 0..3
    int hc = (lane & 3) << 4;     // 16B chunk byte-offset in 64B row
    int n = blk * 16 + (tid >> 6) * 4 + nq;
    bool valid = n < N;

    int beg = valid ? ptr[n] : 0;
    int end = valid ? ptr[n + 1] : 0;
    float d = valid ? dinv[n] : 0.f;

    // group indices 0..5 preloaded (6 srcs loads in flight)
    int s0 = srcs[beg + e];
    int s1 = srcs[beg + 4 + e];
    int s2 = srcs[beg + 8 + e];
    int s3 = srcs[beg + 12 + e];
    int s4 = srcs[beg + 16 + e];
    int s5 = srcs[beg + 20 + e];

    float a[16];
    #pragma unroll
    for (int k = 0; k < 16; ++k) a[k] = 0.f;

    float m1 = (beg + 8  <= end) ? 1.f : 0.f;
    float m2 = (beg + 12 <= end) ? 1.f : 0.f;
    float m3 = (beg + 16 <= end) ? 1.f : 0.f;

    // unconditional group 0..3 gathers (indices always valid via tail pad)
    acc_row(vin + ((size_t)s0 << 6) + hc, 1.f, a);
    acc_row(vin + ((size_t)s1 << 6) + hc, m1, a);
    acc_row(vin + ((size_t)s2 << 6) + hc, m2, a);
    acc_row(vin + ((size_t)s3 << 6) + hc, m3, a);

    // groups 4/5, then rare loop
    if (beg + 20 <= end) {
        acc_row(vin + ((size_t)s4 << 6) + hc, 1.f, a);
        if (beg + 24 <= end) {
            acc_row(vin + ((size_t)s5 << 6) + hc, 1.f, a);
            for (int j = beg + 24; j + 4 <= end; j += 4) {
                int s = srcs[j + e];
                acc_row(vin + ((size_t)s << 6) + hc, 1.f, a);
            }
        }
    }

    // reduce across the 4 edge slots (lane bits 2,3): 2 steps
    #pragma unroll
    for (int k = 0; k < 16; ++k) {
        a[k] += __shfl_xor(a[k], 4);
        a[k] += __shfl_xor(a[k], 8);
    }
    if (e == 0 && valid) {
        float dd = d * d;
        uint4 o;
        int w;
        w = __builtin_amdgcn_cvt_pk_fp8_f32(dd * a[0],  dd * a[1],  0, 0);
        w = __builtin_amdgcn_cvt_pk_fp8_f32(dd * a[2],  dd * a[3],  w, 1);
        o.x = (unsigned)w;
        w = __builtin_amdgcn_cvt_pk_fp8_f32(dd * a[4],  dd * a[5],  0, 0);
        w = __builtin_amdgcn_cvt_pk_fp8_f32(dd * a[6],  dd * a[7],  w, 1);
        o.y = (unsigned)w;
        w = __builtin_amdgcn_cvt_pk_fp8_f32(dd * a[8],  dd * a[9],  0, 0);
        w = __builtin_amdgcn_cvt_pk_fp8_f32(dd * a[10], dd * a[11], w, 1);
        o.z = (unsigned)w;
        w = __builtin_amdgcn_cvt_pk_fp8_f32(dd * a[12], dd * a[13], 0, 0);
        w = __builtin_amdgcn_cvt_pk_fp8_f32(dd * a[14], dd * a[15], w, 1);
        o.w = (unsigned)w;
        *(uint4*)(vout + ((size_t)n << 6) + hc) = o;
    }
}

// ---------------------------------------------------------------------------
// make_wfrag: folded effective weights, fp16, MFMA B-fragment order
// wf[((dt*8 + t)*64 + lane)*8 + j]  (lane = quad*16+col).
// Fold: cat@W = x@W3 + p1@(W0-W3+W4) + p3@(W1-W4+W5) + p7@(W2-W5)
// ---------------------------------------------------------------------------
__global__ void make_wfrag_kernel(const float* __restrict__ W,
                                  _Float16* __restrict__ wf) {
    int idx = blockIdx.x * blockDim.x + threadIdx.x;   // 16384
    if (idx < 16384) {
        int j = idx & 7;
        int lane = (idx >> 3) & 63;
        int t = (idx >> 9) & 7;
        int dt = idx >> 12;
        int col = lane & 15, quad = lane >> 4;
        int d = dt * 16 + col;
        int kk = t * 32 + quad * 8 + j;
        int src = kk >> 6, k = kk & 63;
        float v;
        if (src == 0)      v = W[(3 * 64 + k) * 64 + d];
        else if (src == 1) v = W[(0 * 64 + k) * 64 + d]
                             - W[(3 * 64 + k) * 64 + d]
                             + W[(4 * 64 + k) * 64 + d];
        else if (src == 2) v = W[(1 * 64 + k) * 64 + d]
                             - W[(4 * 64 + k) * 64 + d]
                             + W[(5 * 64 + k) * 64 + d];
        else               v = W[(2 * 64 + k) * 64 + d]
                             - W[(5 * 64 + k) * 64 + d];
        wf[idx] = (_Float16)v;
    }
}

// ---------------------------------------------------------------------------
// MFMA combine: A-fragments for v1/v3/v7 converted from fp8 (8 bytes ->
// 8 floats via HW cvt, scaled by rdinv, packed to fp16); x16 fragment
// unchanged. B-fragments from the 32 KB fragment-ordered wf table.
// ---------------------------------------------------------------------------
__launch_bounds__(256)
__global__ void combine_mfma_kernel(const _Float16* __restrict__ x16,
                                    const unsigned char* __restrict__ v1,
                                    const unsigned char* __restrict__ v3,
                                    const unsigned char* __restrict__ v7,
                                    const float* __restrict__ rdinv,
                                    const _Float16* __restrict__ wf,
                                    const float* __restrict__ bias,
                                    float* __restrict__ out, int N) {
    int tid = threadIdx.x;
    int lane = tid & 63, w = tid >> 6;
    int quad = lane >> 4, col = lane & 15;

    float bv[4];
    #pragma unroll
    for (int dt = 0; dt < 4; ++dt) bv[dt] = bias[dt * 16 + col];

    int bps = (N + 15) / 16;
    for (int g = blockIdx.x * 4 + w; g < bps; g += gridDim.x * 4) {
        int n0 = g * 16;
        int n = n0 + col;
        int nl = (n < N) ? n : 0;
        float rd = rdinv[nl];

        half8 a[8];
        a[0] = *(const half8*)(x16 + (size_t)nl * DIM + quad * 8);
        a[1] = *(const half8*)(x16 + (size_t)nl * DIM + 32 + quad * 8);
        const unsigned char* vs[3] = {v1, v3, v7};
        #pragma unroll
        for (int sI = 0; sI < 3; ++sI) {
            #pragma unroll
            for (int hf = 0; hf < 2; ++hf) {
                int d0 = hf * 32 + quad * 8;           // byte offset (1B/dim)
                uint2 q = *(const uint2*)(vs[sI] + (size_t)nl * 64 + d0);
                floatx2 f0 = __builtin_amdgcn_cvt_pk_f32_fp8(q.x, 0);
                floatx2 f1 = __builtin_amdgcn_cvt_pk_f32_fp8(q.x, 1);
                floatx2 f2 = __builtin_amdgcn_cvt_pk_f32_fp8(q.y, 0);
                floatx2 f3 = __builtin_amdgcn_cvt_pk_f32_fp8(q.y, 1);
                half8 hv;
                hv[0] = (_Float16)(f0[0] * rd); hv[1] = (_Float16)(f0[1] * rd);
                hv[2] = (_Float16)(f1[0] * rd); hv[3] = (_Float16)(f1[1] * rd);
                hv[4] = (_Float16)(f2[0] * rd); hv[5] = (_Float16)(f2[1] * rd);
                hv[6] = (_Float16)(f3[0] * rd); hv[7] = (_Float16)(f3[1] * rd);
                a[2 + sI * 2 + hf] = hv;
            }
        }

        floatx4 acc[4];
        #pragma unroll
        for (int dt = 0; dt < 4; ++dt) {
            floatx4 z = {bv[dt], bv[dt], bv[dt], bv[dt]};
            acc[dt] = z;
        }
        #pragma unroll
        for (int t = 0; t < 8; ++t) {
            #pragma unroll
            for (int dt = 0; dt < 4; ++dt) {
                half8 bf = *(const half8*)(wf + (((dt * 8 + t) * 64 + lane) << 3));
                acc[dt] = __builtin_amdgcn_mfma_f32_16x16x32_f16(
                    a[t], bf, acc[dt], 0, 0, 0);
            }
        }

        #pragma unroll
        for (int dt = 0; dt < 4; ++dt)
            #pragma unroll
            for (int r = 0; r < 4; ++r) {
                int nn = n0 + quad * 4 + r;
                if (nn < N)
                    out[(size_t)nn * DIM + dt * 16 + col] =
                        fmaxf(acc[dt][r], 0.f);
            }
    }
}

extern "C" void kernel_launch(void* const* d_in, const int* in_sizes, int n_in,
                              void* d_out, int out_size, void* d_ws, size_t ws_size,
                              hipStream_t stream) {
    const float* x  = (const float*)d_in[0];
    const int*   ei = (const int*)d_in[1];
    const float* W  = (const float*)d_in[2];
    const float* b  = (const float*)d_in[3];
    float* out = (float*)d_out;

    const int N = in_sizes[0] / DIM;
    const int E = in_sizes[1] / 2;
    const int* row = ei;
    const int* col = ei + E;

    const int nbins = (N + 255) >> BIN_SHIFT;
    const int nbE = (E + 4095) / 4096;    // edge blocks (<=512 assumed)
    const int nblk = (N + 15) / 16;       // spmv blocks (16 nodes each)
    const size_t VB = (size_t)(N + 1) * 64;   // bytes per fp8 value buffer

    int2* staging = (int2*)d_ws;                          // 512*BCAP
    float* dinv  = (float*)(staging + (size_t)512 * BCAP);
    float* rdinv = dinv + N;
    _Float16* wf  = (_Float16*)(rdinv + N);               // 16384 halves
    _Float16* x16 = wf + 16384;                           // (N+16)*64
    unsigned char* v0 = (unsigned char*)(x16 + (size_t)(N + 16) * 64);
    unsigned char* v1 = v0 + VB;
    unsigned char* v3 = v1 + VB;
    unsigned char* v7 = v3 + VB;
    unsigned char* T1 = v7 + VB;
    unsigned char* T2 = T1 + VB;
    int* deg = (int*)(T2 + VB);           // N
    int* ptr = deg + N;                   // N+1
    int* bs  = ptr + N + 1;               // <=1024
    int* bin_cursor = bs + 1024;          // 512
    int* srcs = bin_cursor + 512;         // E + 4N + 64 tail pad
    int* blockhist = srcs + (size_t)E + 4 * (size_t)N + 64;  // 512*512
    int* offs_g = blockhist + (size_t)512 * 512;             // 512*512

    // --- binning: hist -> per-bin scan over blocks -> atomic-free scatter ---
    hist_kernel<<<nbE, 256, 0, stream>>>(col, blockhist, E);
    scan_hist_kernel<<<512, 256, 0, stream>>>(blockhist, offs_g,
                                              bin_cursor, nbE);
    scatter_edges_kernel<<<nbE, 256, 0, stream>>>(row, col, offs_g,
                                                  staging, E);
    // --- per-bin degree + dinv/rdinv + padded chunk sums ---
    count_deg_bins_kernel<<<nbins, 256, 0, stream>>>(staging, bin_cursor,
                                                     deg, dinv, rdinv, bs, N);
    // --- scan of chunk sums, then per-chunk prefix -> ptr ---
    scan_block_sums_kernel<<<1, 1024, 0, stream>>>(bs, nbins);
    scan_chunks_kernel<<<nbins, 256, 0, stream>>>(deg, bs, ptr, N);
    // --- CSC fill from bins (self-edge + edges + dummy pads + tail pad) ---
    fill_bins_kernel<<<nbins, 256, 0, stream>>>(staging, bin_cursor, ptr,
                                                srcs, N, N);
    // --- fragment-ordered folded weights ---
    make_wfrag_kernel<<<64, 256, 0, stream>>>(W, wf);
    // --- v0 (fp8) + x16 + dummy-row zeroing ---
    scale_init_slab_kernel<<<(N * 16 + 96 + 255) / 256, 256, 0, stream>>>(
        x, dinv, v0, x16, v1, v3, v7, T1, T2, N);

    auto prop = [&](const unsigned char* src, unsigned char* dst) {
        spmv_fp8_kernel<<<nblk, 256, 0, stream>>>(ptr, srcs, dinv,
                                                  src, dst, N);
    };
    prop(v0, v1);   // A^1
    prop(v1, T1);   // A^2
    prop(T1, v3);   // A^3
    prop(v3, T1);   // A^4
    prop(T1, T2);   // A^5
    prop(T2, T1);   // A^6
    prop(T1, v7);   // A^7

    // --- combine (MFMA, fragment-table B, fp8 A-fragments, no LDS) ---
    combine_mfma_kernel<<<1024, 256, 0, stream>>>(x16, v1, v3, v7, rdinv,
                                                  wf, b, out, N);
}